// Round 7
// baseline (47.029 us; speedup 1.0000x reference)
//
#include <hip/hip_runtime.h>
#include <float.h>

#define Bsz 2048
#define Nn  1024
#define Dd  256

typedef __attribute__((ext_vector_type(8))) short bf16x8;
typedef __attribute__((ext_vector_type(4))) float f32x4;
typedef unsigned long long u64;

// round-to-nearest-even f32 -> bf16 bits
__device__ __forceinline__ unsigned short bfr(float x) {
    unsigned u = __float_as_uint(x);
    u += 0x7fffu + ((u >> 16) & 1u);
    return (unsigned short)(u >> 16);
}
__device__ __forceinline__ float bf2f(unsigned short h) {
    return __uint_as_float(((unsigned)h) << 16);
}

__device__ __forceinline__ void som_params(const int* __restrict__ step,
                                           const int* __restrict__ total,
                                           float* taxa, float* inv2s2) {
    float frac = (float)(*step) / (float)(*total);
    float e = __expf(-frac);
    *taxa = 0.5f * e;
    float sigma = 16.0f * e;              // SIGMA_INICIAL = 16
    *inv2s2 = 1.0f / (2.0f * sigma * sigma);
}

// sortable-u32 encoding of f32 (monotone), packed with index; min => argmin
// with first-index (lowest n) tie-break, matching jnp.argmin.
__device__ __forceinline__ u64 packsc(float f, int n) {
    unsigned u = __float_as_uint(f);
    u = (u & 0x80000000u) ? ~u : (u | 0x80000000u);
    return ((u64)u << 32) | (unsigned)n;
}

// ---------------------------------------------------------------------------
// prep (384 blocks): [0,256) W hi/lo split + w2; [256,384) X hi/lo split +
// bf16 transpose Xt[d][b] + bmin init.
// ---------------------------------------------------------------------------
__global__ __launch_bounds__(256) void prep_all(
    const float* __restrict__ X, const float* __restrict__ W,
    ushort* __restrict__ Xhi, ushort* __restrict__ Xlo,
    ushort* __restrict__ Whi, ushort* __restrict__ Wlo,
    ushort* __restrict__ Xt, float* __restrict__ w2,
    u64* __restrict__ bmin)
{
    __shared__ float ld[64][65];
    const int t = threadIdx.x;
    const int bid = blockIdx.x;

    if (bid < 256) {
        // W: 4 rows/block, one wave per row
        int row  = bid * 4 + (t >> 6);
        int lane = t & 63;
        float4 v = ((const float4*)(W + (size_t)row * Dd))[lane];
        float s = v.x*v.x + v.y*v.y + v.z*v.z + v.w*v.w;
        #pragma unroll
        for (int m = 32; m; m >>= 1) s += __shfl_xor(s, m, 64);
        if (lane == 0) w2[row] = s;
        ushort4 h4, l4;
        h4.x = bfr(v.x); l4.x = bfr(v.x - bf2f(h4.x));
        h4.y = bfr(v.y); l4.y = bfr(v.y - bf2f(h4.y));
        h4.z = bfr(v.z); l4.z = bfr(v.z - bf2f(h4.z));
        h4.w = bfr(v.w); l4.w = bfr(v.w - bf2f(h4.w));
        *(ushort4*)&Whi[(size_t)row * Dd + lane * 4] = h4;
        *(ushort4*)&Wlo[(size_t)row * Dd + lane * 4] = l4;
    } else {
        // X: 64b x 64d tile split + transpose
        const int idx = bid - 256;
        const int b0 = (idx & 31) * 64;
        const int d0 = (idx >> 5) * 64;

        if ((idx >> 5) == 0 && t < 64) bmin[b0 + t] = ~0ull;

        #pragma unroll
        for (int p = 0; p < 4; ++p) {
            int flat = p * 256 + t;
            int row = flat >> 4, c4 = flat & 15;
            float4 v = *(const float4*)&X[(size_t)(b0 + row) * Dd + d0 + c4 * 4];
            ushort4 h4, l4;
            h4.x = bfr(v.x); l4.x = bfr(v.x - bf2f(h4.x));
            h4.y = bfr(v.y); l4.y = bfr(v.y - bf2f(h4.y));
            h4.z = bfr(v.z); l4.z = bfr(v.z - bf2f(h4.z));
            h4.w = bfr(v.w); l4.w = bfr(v.w - bf2f(h4.w));
            size_t off = (size_t)(b0 + row) * Dd + d0 + c4 * 4;
            *(ushort4*)&Xhi[off] = h4;
            *(ushort4*)&Xlo[off] = l4;
            ld[row][c4*4+0] = v.x; ld[row][c4*4+1] = v.y;
            ld[row][c4*4+2] = v.z; ld[row][c4*4+3] = v.w;
        }
        __syncthreads();
        #pragma unroll
        for (int q = 0; q < 2; ++q) {
            int idx2 = q * 256 + t;
            int d  = idx2 >> 3;
            int bs = (idx2 & 7) * 8;
            bf16x8 o;
            #pragma unroll
            for (int j = 0; j < 8; ++j) o[j] = (short)bfr(ld[bs + j][d]);
            *(bf16x8*)&Xt[(size_t)(d0 + d) * Bsz + b0 + bs] = o;
        }
    }
}

// ---------------------------------------------------------------------------
// BMU: score[b][n] = w2[n] - 2*dot(X[b],W[n]) via hi/lo-split MFMA;
// packed atomicMin(u64) -> bmin[b].
// grid (32 b-tiles of 64, 16 n-tiles of 64), block 256 = 4 waves;
// wave w owns n-slice n0 + w*16 (4 M-frags x 1 N-frag, 12 MFMA/kd-step).
// 512 blocks -> 2 blocks/CU, 2 waves/SIMD.
// ---------------------------------------------------------------------------
__global__ __launch_bounds__(256) void bmu_mfma(
    const ushort* __restrict__ Xhi, const ushort* __restrict__ Xlo,
    const ushort* __restrict__ Whi, const ushort* __restrict__ Wlo,
    const float* __restrict__ w2, u64* __restrict__ bmin)
{
    const int t = threadIdx.x, w = t >> 6, l = t & 63;
    const int b0 = blockIdx.x * 64;
    const int n0 = blockIdx.y * 64 + w * 16;
    const int lr = l & 15, lg = l >> 4;

    f32x4 acc[4];
    #pragma unroll
    for (int m = 0; m < 4; ++m) { f32x4 z = {0.f,0.f,0.f,0.f}; acc[m] = z; }

    #pragma unroll
    for (int kd = 0; kd < Dd; kd += 32) {
        bf16x8 ah[4], al[4], bh, bl;
        #pragma unroll
        for (int m = 0; m < 4; ++m) {
            size_t off = (size_t)(b0 + m*16 + lr) * Dd + kd + lg*8;
            ah[m] = *(const bf16x8*)&Xhi[off];
            al[m] = *(const bf16x8*)&Xlo[off];
        }
        size_t offb = (size_t)(n0 + lr) * Dd + kd + lg*8;
        bh = *(const bf16x8*)&Whi[offb];
        bl = *(const bf16x8*)&Wlo[offb];
        #pragma unroll
        for (int m = 0; m < 4; ++m) {
            acc[m] = __builtin_amdgcn_mfma_f32_16x16x32_bf16(ah[m], bh, acc[m], 0, 0, 0);
            acc[m] = __builtin_amdgcn_mfma_f32_16x16x32_bf16(ah[m], bl, acc[m], 0, 0, 0);
            acc[m] = __builtin_amdgcn_mfma_f32_16x16x32_bf16(al[m], bh, acc[m], 0, 0, 0);
        }
    }

    const int nidx = n0 + lr;
    const float w2v = w2[nidx];

    #pragma unroll
    for (int m = 0; m < 4; ++m)
        #pragma unroll
        for (int r = 0; r < 4; ++r) {
            u64 pm = packsc(w2v - 2.f * acc[m][r], nidx);
            #pragma unroll
            for (int msk = 1; msk < 16; msk <<= 1) {
                unsigned plo = (unsigned)pm, phi = (unsigned)(pm >> 32);
                plo = __shfl_xor(plo, msk, 64);
                phi = __shfl_xor(phi, msk, 64);
                u64 o = ((u64)phi << 32) | plo;
                if (o < pm) pm = o;
            }
            if (lr == 0) atomicMin(&bmin[b0 + m*16 + lg*4 + r], pm);
        }
}

// ---------------------------------------------------------------------------
// acc + finish with on-the-fly h:
// out[n][d] = W + taxa*((h@X)[n][d] - hsum[n]*W)/B
// grid (64 n-tiles of 16, 8 d-tiles of 32); block 512 = 8 waves.
// Wave w: full 16n x 32d tile over b-chunk of 256 (in-block split-K).
// 512 blocks -> 2 blocks/CU -> 4 waves/SIMD; per-wave expf halved vs R5.
// ---------------------------------------------------------------------------
__global__ __launch_bounds__(512) void acc_finish(
    const ushort* __restrict__ Xt, const u64* __restrict__ bmin,
    const float* __restrict__ W, const int* __restrict__ step,
    const int* __restrict__ total, float* __restrict__ out)
{
    __shared__ float red[8][16][36];   // [wave][n][d] +4 pad (2-way max)
    __shared__ float hws[8][16];       // per-wave hsum partials

    const int t = threadIdx.x, w = t >> 6, l = t & 63;
    const int lr = l & 15, lg = l >> 4;
    const int n0 = blockIdx.x * 16;
    const int d0 = blockIdx.y * 32;

    float taxa, inv2s2;
    som_params(step, total, &taxa, &inv2s2);

    // lane's n row: n = n0 + lr; rows [n0, n0+16) lie in one 32-aligned half
    const float fny = (float)(n0 >> 5);
    const float fnx = (float)((n0 & 31) + lr);

    f32x4 acc0 = {0.f,0.f,0.f,0.f}, acc1 = {0.f,0.f,0.f,0.f};
    float hs = 0.f;

    #pragma unroll
    for (int ks = 0; ks < 8; ++ks) {
        const int bk = w * 256 + ks * 32 + lg * 8;
        bf16x8 am;
        #pragma unroll
        for (int j = 0; j < 8; ++j) {
            unsigned idx = (unsigned)(bmin[bk + j] & 0xffffffffu);
            float bx = (float)(idx & 31), by = (float)(idx >> 5);
            float dx = fnx - bx, dy = fny - by;
            float h = __expf(-(dx*dx + dy*dy) * inv2s2);
            am[j] = (short)bfr(h);
            hs += h;
        }
        bf16x8 bx0 = *(const bf16x8*)&Xt[(size_t)(d0 + lr)      * Bsz + bk];
        bf16x8 bx1 = *(const bf16x8*)&Xt[(size_t)(d0 + 16 + lr) * Bsz + bk];
        acc0 = __builtin_amdgcn_mfma_f32_16x16x32_bf16(am, bx0, acc0, 0, 0, 0);
        acc1 = __builtin_amdgcn_mfma_f32_16x16x32_bf16(am, bx1, acc1, 0, 0, 0);
    }

    // hsum partials: reduce over lg (same n, different b)
    hs += __shfl_xor(hs, 16, 64);
    hs += __shfl_xor(hs, 32, 64);
    if (l < 16) hws[w][l] = hs;

    // stash per-wave MFMA partials
    #pragma unroll
    for (int r = 0; r < 4; ++r) {
        red[w][lg*4 + r][lr]      = acc0[r];
        red[w][lg*4 + r][16 + lr] = acc1[r];
    }
    __syncthreads();

    // reduce 8 waves + fused epilogue: 512 threads x 1 output each
    const float invB = 1.0f / 2048.0f;
    const int nl = t >> 5;          // 0..15
    const int dl = t & 31;          // 0..31
    float s = 0.f, hsn = 0.f;
    #pragma unroll
    for (int ww = 0; ww < 8; ++ww) {
        s   += red[ww][nl][dl];
        hsn += hws[ww][nl];
    }
    const int n = n0 + nl;
    const int d = d0 + dl;
    const float wv = W[(size_t)n * Dd + d];
    out[(size_t)n * Dd + d] = wv + taxa * (s - hsn * wv) * invB;
}

// ---------------------------------------------------------------------------
extern "C" void kernel_launch(void* const* d_in, const int* in_sizes, int n_in,
                              void* d_out, int out_size, void* d_ws, size_t ws_size,
                              hipStream_t stream)
{
    const float* X    = (const float*)d_in[0];
    const float* W    = (const float*)d_in[1];
    const int* step   = (const int*)d_in[3];
    const int* total  = (const int*)d_in[4];
    float* out = (float*)d_out;

    // workspace (~4.03 MB)
    char* p = (char*)d_ws;
    float* w2   = (float*)p;  p += 4096;
    u64*   bmin = (u64*)p;    p += 16384;
    ushort* Xt  = (ushort*)p; p += 1048576;
    ushort* Xhi = (ushort*)p; p += 1048576;
    ushort* Xlo = (ushort*)p; p += 1048576;
    ushort* Whi = (ushort*)p; p += 524288;
    ushort* Wlo = (ushort*)p; p += 524288;

    prep_all  <<<384, 256, 0, stream>>>(X, W, Xhi, Xlo, Whi, Wlo, Xt, w2, bmin);
    bmu_mfma  <<<dim3(32, 16), 256, 0, stream>>>(Xhi, Xlo, Whi, Wlo, w2, bmin);
    acc_finish<<<dim3(64, 8), 512, 0, stream>>>(Xt, bmin, W, step, total, out);
}

// Round 8
// 36.184 us; speedup vs baseline: 1.2997x; 1.2997x over previous
//
#include <hip/hip_runtime.h>
#include <float.h>

#define Bsz 2048
#define Nn  1024
#define Dd  256

typedef __attribute__((ext_vector_type(8))) short bf16x8;
typedef __attribute__((ext_vector_type(4))) float f32x4;
typedef unsigned long long u64;

// round-to-nearest-even f32 -> bf16 bits
__device__ __forceinline__ unsigned short bfr(float x) {
    unsigned u = __float_as_uint(x);
    u += 0x7fffu + ((u >> 16) & 1u);
    return (unsigned short)(u >> 16);
}
__device__ __forceinline__ float bf2f(unsigned short h) {
    return __uint_as_float(((unsigned)h) << 16);
}

__device__ __forceinline__ void som_params(const int* __restrict__ step,
                                           const int* __restrict__ total,
                                           float* taxa, float* inv2s2) {
    float frac = (float)(*step) / (float)(*total);
    float e = __expf(-frac);
    *taxa = 0.5f * e;
    float sigma = 16.0f * e;              // SIGMA_INICIAL = 16
    *inv2s2 = 1.0f / (2.0f * sigma * sigma);
}

// sortable-u32 encoding of f32 (monotone), packed with index; min => argmin
// with first-index (lowest n) tie-break, matching jnp.argmin.
__device__ __forceinline__ u64 packsc(float f, int n) {
    unsigned u = __float_as_uint(f);
    u = (u & 0x80000000u) ? ~u : (u | 0x80000000u);
    return ((u64)u << 32) | (unsigned)n;
}

// in-register hi/lo bf16 split of 8 consecutive f32; returns sum of squares
__device__ __forceinline__ float split8(const float* __restrict__ src,
                                        bf16x8* hi, bf16x8* lo) {
    float4 v0 = *(const float4*)src;
    float4 v1 = *(const float4*)(src + 4);
    float f[8] = {v0.x, v0.y, v0.z, v0.w, v1.x, v1.y, v1.z, v1.w};
    float s = 0.f;
    #pragma unroll
    for (int j = 0; j < 8; ++j) {
        unsigned short h = bfr(f[j]);
        (*hi)[j] = (short)h;
        (*lo)[j] = (short)bfr(f[j] - bf2f(h));
        s += f[j] * f[j];
    }
    return s;
}

// ---------------------------------------------------------------------------
// Kernel 1 (384 blocks):
//  [0,256)  : BMU partials from RAW f32 X,W — in-register hi/lo split,
//             in-register w2; block tile 128b x 64n (waves: wm=b-half,
//             wn=n-half); writes packed min per (n-tile, b) to ppack.
//  [256,384): Xt[d][b] = bf16(X[b][d]) transpose.
// ---------------------------------------------------------------------------
__global__ __launch_bounds__(256) void fused_pre(
    const float* __restrict__ X, const float* __restrict__ W,
    ushort* __restrict__ Xt, u64* __restrict__ ppack)
{
    __shared__ float ld[64][65];
    __shared__ u64 lmin[2][2][64];     // [wm][wn][b_local]

    const int t = threadIdx.x, bid = blockIdx.x;
    const int w = t >> 6, l = t & 63;
    const int lr = l & 15, lg = l >> 4;

    if (bid < 256) {
        const int wm = w & 1, wn = w >> 1;
        const int b0 = (bid >> 4) * 128 + wm * 64;
        const int n0 = (bid & 15) * 64 + wn * 32;

        f32x4 acc[4][2];
        #pragma unroll
        for (int m = 0; m < 4; ++m)
            #pragma unroll
            for (int n = 0; n < 2; ++n) { f32x4 z = {0.f,0.f,0.f,0.f}; acc[m][n] = z; }
        float w2a[2] = {0.f, 0.f};

        #pragma unroll
        for (int kd = 0; kd < Dd; kd += 32) {
            bf16x8 ah[4], al[4], bh[2], bl[2];
            #pragma unroll
            for (int m = 0; m < 4; ++m)
                split8(&X[(size_t)(b0 + m*16 + lr) * Dd + kd + lg*8], &ah[m], &al[m]);
            #pragma unroll
            for (int nf = 0; nf < 2; ++nf)
                w2a[nf] += split8(&W[(size_t)(n0 + nf*16 + lr) * Dd + kd + lg*8],
                                  &bh[nf], &bl[nf]);
            #pragma unroll
            for (int m = 0; m < 4; ++m)
                #pragma unroll
                for (int nf = 0; nf < 2; ++nf) {
                    acc[m][nf] = __builtin_amdgcn_mfma_f32_16x16x32_bf16(ah[m], bh[nf], acc[m][nf], 0, 0, 0);
                    acc[m][nf] = __builtin_amdgcn_mfma_f32_16x16x32_bf16(ah[m], bl[nf], acc[m][nf], 0, 0, 0);
                    acc[m][nf] = __builtin_amdgcn_mfma_f32_16x16x32_bf16(al[m], bh[nf], acc[m][nf], 0, 0, 0);
                }
        }

        // w2: butterfly over the 4 lg groups (each summed a k-slice of row lr)
        #pragma unroll
        for (int nf = 0; nf < 2; ++nf) {
            w2a[nf] += __shfl_xor(w2a[nf], 16, 64);
            w2a[nf] += __shfl_xor(w2a[nf], 32, 64);
        }
        const int ni0 = n0 + lr, ni1 = n0 + 16 + lr;

        #pragma unroll
        for (int m = 0; m < 4; ++m)
            #pragma unroll
            for (int r = 0; r < 4; ++r) {
                u64 p0 = packsc(w2a[0] - 2.f * acc[m][0][r], ni0);
                u64 p1 = packsc(w2a[1] - 2.f * acc[m][1][r], ni1);
                u64 pm = p1 < p0 ? p1 : p0;
                #pragma unroll
                for (int msk = 1; msk < 16; msk <<= 1) {
                    unsigned plo = (unsigned)pm, phi = (unsigned)(pm >> 32);
                    plo = __shfl_xor(plo, msk, 64);
                    phi = __shfl_xor(phi, msk, 64);
                    u64 o = ((u64)phi << 32) | plo;
                    if (o < pm) pm = o;
                }
                if (lr == 0) lmin[wm][wn][m*16 + lg*4 + r] = pm;
            }
        __syncthreads();
        if (t < 128) {
            const int bwm = t >> 6, bb = t & 63;
            u64 a = lmin[bwm][0][bb], c = lmin[bwm][1][bb];
            u64 pm = c < a ? c : a;
            const int b = (bid >> 4) * 128 + bwm * 64 + bb;
            ppack[(size_t)(bid & 15) * Bsz + b] = pm;
        }
    } else {
        // ---- Xt transpose role (128 blocks) ----
        const int idx = bid - 256;
        const int b0 = (idx & 31) * 64;
        const int d0 = (idx >> 5) * 64;

        #pragma unroll
        for (int p = 0; p < 4; ++p) {
            int flat = p * 256 + t;
            int row = flat >> 4, c4 = flat & 15;
            float4 v = *(const float4*)&X[(size_t)(b0 + row) * Dd + d0 + c4 * 4];
            ld[row][c4*4+0] = v.x; ld[row][c4*4+1] = v.y;
            ld[row][c4*4+2] = v.z; ld[row][c4*4+3] = v.w;
        }
        __syncthreads();
        #pragma unroll
        for (int q = 0; q < 2; ++q) {
            int idx2 = q * 256 + t;
            int d  = idx2 >> 3;
            int bs = (idx2 & 7) * 8;
            bf16x8 o;
            #pragma unroll
            for (int j = 0; j < 8; ++j) o[j] = (short)bfr(ld[bs + j][d]);
            *(bf16x8*)&Xt[(size_t)(d0 + d) * Bsz + b0 + bs] = o;
        }
    }
}

// ---------------------------------------------------------------------------
// Kernel 2: final argmin (redundant per block, into LDS) + acc + finish.
// out[n][d] = W + taxa*((h@X)[n][d] - hsum[n]*W)/B
// grid (32 n-tiles of 32, 8 d-tiles of 32); block 512 = 8 waves;
// wave w: full 32n x 32d tile over b-chunk of 256 (in-block split-K);
// h generated per-lane in A-frag layout; hsum exact in-block.
// ---------------------------------------------------------------------------
__global__ __launch_bounds__(512) void acc_finish(
    const ushort* __restrict__ Xt, const u64* __restrict__ ppack,
    const float* __restrict__ W, const int* __restrict__ step,
    const int* __restrict__ total, float* __restrict__ out)
{
    __shared__ float red[8][32][36];   // [wave][n][d] +4 pad
    __shared__ float hws[8][32];       // per-wave hsum partials
    __shared__ ushort bidx[Bsz];       // final BMU index per b

    const int t = threadIdx.x, w = t >> 6, l = t & 63;
    const int lr = l & 15, lg = l >> 4;
    const int n0 = blockIdx.x * 32;
    const int d0 = blockIdx.y * 32;

    // ---- prologue: reduce 16 partials per b (coalesced, deterministic) ----
    #pragma unroll
    for (int q = 0; q < 4; ++q) {
        const int b = q * 512 + t;
        u64 pm = ppack[b];
        #pragma unroll
        for (int g = 1; g < 16; ++g) {
            u64 c = ppack[(size_t)g * Bsz + b];
            if (c < pm) pm = c;
        }
        bidx[b] = (ushort)(pm & 0xffffu);
    }
    __syncthreads();

    float taxa, inv2s2;
    som_params(step, total, &taxa, &inv2s2);

    // lane's two n rows: n = n0 + m*16 + lr  ->  nx = m*16+lr, ny = n0>>5
    const float fny  = (float)(n0 >> 5);
    const float fnx0 = (float)lr;
    const float fnx1 = (float)(lr + 16);

    f32x4 acc[2][2];
    #pragma unroll
    for (int m = 0; m < 2; ++m)
        #pragma unroll
        for (int nf = 0; nf < 2; ++nf) { f32x4 z = {0.f,0.f,0.f,0.f}; acc[m][nf] = z; }
    float hs0 = 0.f, hs1 = 0.f;

    #pragma unroll
    for (int ks = 0; ks < 8; ++ks) {
        const int bk = w * 256 + ks * 32 + lg * 8;
        bf16x8 am0, am1;
        #pragma unroll
        for (int j = 0; j < 8; ++j) {
            unsigned idx = bidx[bk + j];
            float bx = (float)(idx & 31), by = (float)(idx >> 5);
            float dy  = fny - by;
            float dy2 = dy * dy;
            float dx0 = fnx0 - bx, dx1 = fnx1 - bx;
            float h0 = __expf(-(dx0*dx0 + dy2) * inv2s2);
            float h1 = __expf(-(dx1*dx1 + dy2) * inv2s2);
            am0[j] = (short)bfr(h0);
            am1[j] = (short)bfr(h1);
            hs0 += h0; hs1 += h1;
        }
        bf16x8 bx0 = *(const bf16x8*)&Xt[(size_t)(d0 + lr)      * Bsz + bk];
        bf16x8 bx1 = *(const bf16x8*)&Xt[(size_t)(d0 + 16 + lr) * Bsz + bk];
        acc[0][0] = __builtin_amdgcn_mfma_f32_16x16x32_bf16(am0, bx0, acc[0][0], 0, 0, 0);
        acc[0][1] = __builtin_amdgcn_mfma_f32_16x16x32_bf16(am0, bx1, acc[0][1], 0, 0, 0);
        acc[1][0] = __builtin_amdgcn_mfma_f32_16x16x32_bf16(am1, bx0, acc[1][0], 0, 0, 0);
        acc[1][1] = __builtin_amdgcn_mfma_f32_16x16x32_bf16(am1, bx1, acc[1][1], 0, 0, 0);
    }

    // hsum partials: reduce over lg (same n, different b)
    hs0 += __shfl_xor(hs0, 16, 64); hs0 += __shfl_xor(hs0, 32, 64);
    hs1 += __shfl_xor(hs1, 16, 64); hs1 += __shfl_xor(hs1, 32, 64);
    if (l < 16) { hws[w][l] = hs0; hws[w][16 + l] = hs1; }

    // stash per-wave MFMA partials
    #pragma unroll
    for (int m = 0; m < 2; ++m)
        #pragma unroll
        for (int nf = 0; nf < 2; ++nf)
            #pragma unroll
            for (int r = 0; r < 4; ++r)
                red[w][m*16 + lg*4 + r][nf*16 + lr] = acc[m][nf][r];
    __syncthreads();

    // reduce 8 waves + fused epilogue: 512 threads x 2 outputs (float2)
    const float invB = 1.0f / 2048.0f;
    const int nl = t >> 4;          // 0..31
    const int dl = (t & 15) * 2;    // 0,2,..,30
    float s0 = 0.f, s1 = 0.f, hsn = 0.f;
    #pragma unroll
    for (int ww = 0; ww < 8; ++ww) {
        s0  += red[ww][nl][dl];
        s1  += red[ww][nl][dl + 1];
        hsn += hws[ww][nl];
    }
    const int n = n0 + nl;
    const int d = d0 + dl;
    const float* wp = &W[(size_t)n * Dd + d];
    float wv0 = wp[0], wv1 = wp[1];
    float2 o = make_float2(wv0 + taxa * (s0 - hsn * wv0) * invB,
                           wv1 + taxa * (s1 - hsn * wv1) * invB);
    *(float2*)&out[(size_t)n * Dd + d] = o;
}

// ---------------------------------------------------------------------------
extern "C" void kernel_launch(void* const* d_in, const int* in_sizes, int n_in,
                              void* d_out, int out_size, void* d_ws, size_t ws_size,
                              hipStream_t stream)
{
    const float* X    = (const float*)d_in[0];
    const float* W    = (const float*)d_in[1];
    const int* step   = (const int*)d_in[3];
    const int* total  = (const int*)d_in[4];
    float* out = (float*)d_out;

    // workspace (~1.28 MB): Xt bf16 [256][2048] | ppack u64 [16][2048]
    char* p = (char*)d_ws;
    ushort* Xt   = (ushort*)p; p += 1048576;
    u64*    ppack = (u64*)p;   p += 262144;

    fused_pre <<<384, 256, 0, stream>>>(X, W, Xt, ppack);
    acc_finish<<<dim3(32, 8), 512, 0, stream>>>(Xt, ppack, W, step, total, out);
}

// Round 9
// 35.915 us; speedup vs baseline: 1.3095x; 1.0075x over previous
//
#include <hip/hip_runtime.h>
#include <float.h>

#define Bsz 2048
#define Nn  1024
#define Dd  256

typedef __attribute__((ext_vector_type(8))) short bf16x8;
typedef __attribute__((ext_vector_type(4))) float f32x4;
typedef unsigned long long u64;

union b8u4 { bf16x8 v; uint4 u; };

// round-to-nearest-even f32 -> bf16 bits (used only for Xt)
__device__ __forceinline__ unsigned short bfr(float x) {
    unsigned u = __float_as_uint(x);
    u += 0x7fffu + ((u >> 16) & 1u);
    return (unsigned short)(u >> 16);
}

__device__ __forceinline__ void som_params(const int* __restrict__ step,
                                           const int* __restrict__ total,
                                           float* taxa, float* inv2s2) {
    float frac = (float)(*step) / (float)(*total);
    float e = __expf(-frac);
    *taxa = 0.5f * e;
    float sigma = 16.0f * e;              // SIGMA_INICIAL = 16
    *inv2s2 = 1.0f / (2.0f * sigma * sigma);
}

// sortable-u32 encoding of f32 (monotone), packed with index; min => argmin
// with first-index (lowest n) tie-break, matching jnp.argmin.
__device__ __forceinline__ u64 packsc(float f, int n) {
    unsigned u = __float_as_uint(f);
    u = (u & 0x80000000u) ? ~u : (u | 0x80000000u);
    return ((u64)u << 32) | (unsigned)n;
}

// cheap TRUNCATION hi/lo split of 8 consecutive f32, pair-packed (~6 ops/elem);
// 3-MFMA correction absorbs the larger truncation-lo. returns sum of squares.
__device__ __forceinline__ float split8t(const float* __restrict__ src,
                                         bf16x8* hi, bf16x8* lo) {
    float4 v0 = *(const float4*)src;
    float4 v1 = *(const float4*)(src + 4);
    float f[8] = {v0.x, v0.y, v0.z, v0.w, v1.x, v1.y, v1.z, v1.w};
    float s = 0.f;
    unsigned hp[4], lp[4];
    #pragma unroll
    for (int p = 0; p < 4; ++p) {
        float a = f[2*p], b = f[2*p+1];
        unsigned ua = __float_as_uint(a), ub = __float_as_uint(b);
        unsigned ha = ua & 0xffff0000u, hb = ub & 0xffff0000u;
        float la = a - __uint_as_float(ha);
        float lb = b - __uint_as_float(hb);
        hp[p] = (ua >> 16) | hb;
        lp[p] = (__float_as_uint(la) >> 16) | (__float_as_uint(lb) & 0xffff0000u);
        s = fmaf(a, a, s); s = fmaf(b, b, s);
    }
    b8u4 H, L;
    H.u = make_uint4(hp[0], hp[1], hp[2], hp[3]);
    L.u = make_uint4(lp[0], lp[1], lp[2], lp[3]);
    *hi = H.v; *lo = L.v;
    return s;
}

// ---------------------------------------------------------------------------
// Kernel 1 (384 blocks, 256 thr):
//  [0,256)  : BMU partials from RAW f32 X,W — cheap in-register split,
//             in-register w2; block tile 128b x 64n; packed min -> ppack.
//  [256,384): Xt[d][b] = bf16(X[b][d]) transpose (RTNE).
// ---------------------------------------------------------------------------
__global__ __launch_bounds__(256) void fused_pre(
    const float* __restrict__ X, const float* __restrict__ W,
    ushort* __restrict__ Xt, u64* __restrict__ ppack)
{
    __shared__ float ld[64][65];
    __shared__ u64 lmin[2][2][64];     // [wm][wn][b_local]

    const int t = threadIdx.x, bid = blockIdx.x;
    const int w = t >> 6, l = t & 63;
    const int lr = l & 15, lg = l >> 4;

    if (bid < 256) {
        const int wm = w & 1, wn = w >> 1;
        const int b0 = (bid >> 4) * 128 + wm * 64;
        const int n0 = (bid & 15) * 64 + wn * 32;

        f32x4 acc[4][2];
        #pragma unroll
        for (int m = 0; m < 4; ++m)
            #pragma unroll
            for (int n = 0; n < 2; ++n) { f32x4 z = {0.f,0.f,0.f,0.f}; acc[m][n] = z; }
        float w2a[2] = {0.f, 0.f};

        #pragma unroll
        for (int kd = 0; kd < Dd; kd += 32) {
            bf16x8 ah[4], al[4], bh[2], bl[2];
            #pragma unroll
            for (int m = 0; m < 4; ++m)
                split8t(&X[(size_t)(b0 + m*16 + lr) * Dd + kd + lg*8], &ah[m], &al[m]);
            #pragma unroll
            for (int nf = 0; nf < 2; ++nf)
                w2a[nf] += split8t(&W[(size_t)(n0 + nf*16 + lr) * Dd + kd + lg*8],
                                   &bh[nf], &bl[nf]);
            #pragma unroll
            for (int m = 0; m < 4; ++m)
                #pragma unroll
                for (int nf = 0; nf < 2; ++nf) {
                    acc[m][nf] = __builtin_amdgcn_mfma_f32_16x16x32_bf16(ah[m], bh[nf], acc[m][nf], 0, 0, 0);
                    acc[m][nf] = __builtin_amdgcn_mfma_f32_16x16x32_bf16(ah[m], bl[nf], acc[m][nf], 0, 0, 0);
                    acc[m][nf] = __builtin_amdgcn_mfma_f32_16x16x32_bf16(al[m], bh[nf], acc[m][nf], 0, 0, 0);
                }
        }

        // w2: butterfly over the 4 lg groups (each summed a k-slice of row lr)
        #pragma unroll
        for (int nf = 0; nf < 2; ++nf) {
            w2a[nf] += __shfl_xor(w2a[nf], 16, 64);
            w2a[nf] += __shfl_xor(w2a[nf], 32, 64);
        }
        const int ni0 = n0 + lr, ni1 = n0 + 16 + lr;

        #pragma unroll
        for (int m = 0; m < 4; ++m)
            #pragma unroll
            for (int r = 0; r < 4; ++r) {
                u64 p0 = packsc(w2a[0] - 2.f * acc[m][0][r], ni0);
                u64 p1 = packsc(w2a[1] - 2.f * acc[m][1][r], ni1);
                u64 pm = p1 < p0 ? p1 : p0;
                #pragma unroll
                for (int msk = 1; msk < 16; msk <<= 1) {
                    unsigned plo = (unsigned)pm, phi = (unsigned)(pm >> 32);
                    plo = __shfl_xor(plo, msk, 64);
                    phi = __shfl_xor(phi, msk, 64);
                    u64 o = ((u64)phi << 32) | plo;
                    if (o < pm) pm = o;
                }
                if (lr == 0) lmin[wm][wn][m*16 + lg*4 + r] = pm;
            }
        __syncthreads();
        if (t < 128) {
            const int bwm = t >> 6, bb = t & 63;
            u64 a = lmin[bwm][0][bb], c = lmin[bwm][1][bb];
            u64 pm = c < a ? c : a;
            const int b = (bid >> 4) * 128 + bwm * 64 + bb;
            ppack[(size_t)(bid & 15) * Bsz + b] = pm;
        }
    } else {
        // ---- Xt transpose role (128 blocks) ----
        const int idx = bid - 256;
        const int b0 = (idx & 31) * 64;
        const int d0 = (idx >> 5) * 64;

        #pragma unroll
        for (int p = 0; p < 4; ++p) {
            int flat = p * 256 + t;
            int row = flat >> 4, c4 = flat & 15;
            float4 v = *(const float4*)&X[(size_t)(b0 + row) * Dd + d0 + c4 * 4];
            ld[row][c4*4+0] = v.x; ld[row][c4*4+1] = v.y;
            ld[row][c4*4+2] = v.z; ld[row][c4*4+3] = v.w;
        }
        __syncthreads();
        #pragma unroll
        for (int q = 0; q < 2; ++q) {
            int idx2 = q * 256 + t;
            int d  = idx2 >> 3;
            int bs = (idx2 & 7) * 8;
            bf16x8 o;
            #pragma unroll
            for (int j = 0; j < 8; ++j) o[j] = (short)bfr(ld[bs + j][d]);
            *(bf16x8*)&Xt[(size_t)(d0 + d) * Bsz + b0 + bs] = o;
        }
    }
}

// ---------------------------------------------------------------------------
// Kernel 2: final argmin + acc + finish, 1024 thr = 16 waves (4 waves/SIMD).
// out[n][d] = W + taxa*((h@X)[n][d] - hsum[n]*W)/B
// grid (32 n-tiles of 32, 8 d-tiles of 32); wave w: 32n x 32d tile over
// b-chunk of 128; h per-lane in A-frag layout; two-stage LDS reduce.
// ---------------------------------------------------------------------------
__global__ __launch_bounds__(1024, 4) void acc_finish(
    const ushort* __restrict__ Xt, const u64* __restrict__ ppack,
    const float* __restrict__ W, const int* __restrict__ step,
    const int* __restrict__ total, float* __restrict__ out)
{
    __shared__ float red[8][32][36];   // 36.9 KB, two-stage (waves 8-15 add)
    __shared__ float hws[16][32];      // per-wave hsum partials
    __shared__ ushort bidx[Bsz];       // final BMU index per b

    const int t = threadIdx.x, w = t >> 6, l = t & 63;
    const int lr = l & 15, lg = l >> 4;
    const int n0 = blockIdx.x * 32;
    const int d0 = blockIdx.y * 32;

    // ---- prologue: reduce 16 partials per b (coalesced, deterministic) ----
    #pragma unroll
    for (int q = 0; q < 2; ++q) {
        const int b = q * 1024 + t;
        u64 pm = ppack[b];
        #pragma unroll
        for (int g = 1; g < 16; ++g) {
            u64 c = ppack[(size_t)g * Bsz + b];
            if (c < pm) pm = c;
        }
        bidx[b] = (ushort)(pm & 0xffffu);
    }
    __syncthreads();

    float taxa, inv2s2;
    som_params(step, total, &taxa, &inv2s2);

    // lane's two n rows: n = n0 + m*16 + lr  ->  nx = m*16+lr, ny = n0>>5
    const float fny  = (float)(n0 >> 5);
    const float fnx0 = (float)lr;
    const float fnx1 = (float)(lr + 16);

    f32x4 acc[2][2];
    #pragma unroll
    for (int m = 0; m < 2; ++m)
        #pragma unroll
        for (int nf = 0; nf < 2; ++nf) { f32x4 z = {0.f,0.f,0.f,0.f}; acc[m][nf] = z; }
    float hs0 = 0.f, hs1 = 0.f;

    #pragma unroll
    for (int ks = 0; ks < 4; ++ks) {
        const int bk = w * 128 + ks * 32 + lg * 8;
        bf16x8 am0, am1;
        #pragma unroll
        for (int j = 0; j < 8; ++j) {
            unsigned idx = bidx[bk + j];
            float bx = (float)(idx & 31), by = (float)(idx >> 5);
            float dy  = fny - by;
            float dy2 = dy * dy;
            float dx0 = fnx0 - bx, dx1 = fnx1 - bx;
            float h0 = __expf(-(dx0*dx0 + dy2) * inv2s2);
            float h1 = __expf(-(dx1*dx1 + dy2) * inv2s2);
            am0[j] = (short)bfr(h0);
            am1[j] = (short)bfr(h1);
            hs0 += h0; hs1 += h1;
        }
        bf16x8 bx0 = *(const bf16x8*)&Xt[(size_t)(d0 + lr)      * Bsz + bk];
        bf16x8 bx1 = *(const bf16x8*)&Xt[(size_t)(d0 + 16 + lr) * Bsz + bk];
        acc[0][0] = __builtin_amdgcn_mfma_f32_16x16x32_bf16(am0, bx0, acc[0][0], 0, 0, 0);
        acc[0][1] = __builtin_amdgcn_mfma_f32_16x16x32_bf16(am0, bx1, acc[0][1], 0, 0, 0);
        acc[1][0] = __builtin_amdgcn_mfma_f32_16x16x32_bf16(am1, bx0, acc[1][0], 0, 0, 0);
        acc[1][1] = __builtin_amdgcn_mfma_f32_16x16x32_bf16(am1, bx1, acc[1][1], 0, 0, 0);
    }

    // hsum partials: reduce over lg (same n, different b)
    hs0 += __shfl_xor(hs0, 16, 64); hs0 += __shfl_xor(hs0, 32, 64);
    hs1 += __shfl_xor(hs1, 16, 64); hs1 += __shfl_xor(hs1, 32, 64);
    if (l < 16) { hws[w][l] = hs0; hws[w][16 + l] = hs1; }

    // two-stage MFMA-partial reduce: waves 0-7 write, waves 8-15 add
    if (w < 8) {
        #pragma unroll
        for (int m = 0; m < 2; ++m)
            #pragma unroll
            for (int nf = 0; nf < 2; ++nf)
                #pragma unroll
                for (int r = 0; r < 4; ++r)
                    red[w][m*16 + lg*4 + r][nf*16 + lr] = acc[m][nf][r];
    }
    __syncthreads();
    if (w >= 8) {
        #pragma unroll
        for (int m = 0; m < 2; ++m)
            #pragma unroll
            for (int nf = 0; nf < 2; ++nf)
                #pragma unroll
                for (int r = 0; r < 4; ++r)
                    red[w - 8][m*16 + lg*4 + r][nf*16 + lr] += acc[m][nf][r];
    }
    __syncthreads();

    // epilogue: 1024 threads x 1 output
    const float invB = 1.0f / 2048.0f;
    const int nl = t >> 5;          // 0..31
    const int dl = t & 31;          // 0..31
    float s = 0.f, hsn = 0.f;
    #pragma unroll
    for (int ww = 0; ww < 8; ++ww) s += red[ww][nl][dl];
    #pragma unroll
    for (int ww = 0; ww < 16; ++ww) hsn += hws[ww][nl];
    const int n = n0 + nl;
    const int d = d0 + dl;
    const float wv = W[(size_t)n * Dd + d];
    out[(size_t)n * Dd + d] = wv + taxa * (s - hsn * wv) * invB;
}

// ---------------------------------------------------------------------------
extern "C" void kernel_launch(void* const* d_in, const int* in_sizes, int n_in,
                              void* d_out, int out_size, void* d_ws, size_t ws_size,
                              hipStream_t stream)
{
    const float* X    = (const float*)d_in[0];
    const float* W    = (const float*)d_in[1];
    const int* step   = (const int*)d_in[3];
    const int* total  = (const int*)d_in[4];
    float* out = (float*)d_out;

    // workspace (~1.28 MB): Xt bf16 [256][2048] | ppack u64 [16][2048]
    char* p = (char*)d_ws;
    ushort* Xt    = (ushort*)p; p += 1048576;
    u64*    ppack = (u64*)p;    p += 262144;

    fused_pre <<<384, 256, 0, stream>>>(X, W, Xt, ppack);
    acc_finish<<<dim3(32, 8), 1024, 0, stream>>>(Xt, ppack, W, step, total, out);
}